// Round 1
// baseline (1259.199 us; speedup 1.0000x reference)
//
#include <hip/hip_runtime.h>

// Equivariant linear: per-irrep block-diagonal matmul.
// Irreps: 256x0e + 128x1o + 64x2e + 32x3o, B = 131072, FEAT = 1184.
// y[b,v,i] = (1/sqrt(mul)) * sum_u w[v,u] * x[b,u,i]
//
// GEMM view per block: M = B*d rows (m = b*d + i), N = K = mul.
// bf16 MFMA 16x16x32; weights held in registers (B-fragments) for the
// lifetime of a persistent workgroup; A-fragments loaded directly from
// global (fp32 -> bf16 cvt in regs). Memory-bound: ~1.24 GB total traffic.

typedef __attribute__((ext_vector_type(8))) __bf16 bf16x8;
typedef __attribute__((ext_vector_type(4))) float f32x4;

constexpr int FEAT = 1184;

template<int MUL, int D, int XO, int WO, int WAVES_M, int WAVES_N, int NT>
__global__ __launch_bounds__(256, 2)
void eqlin(const float* __restrict__ x, const float* __restrict__ w,
           float* __restrict__ out, int n_tiles, float cnorm)
{
    constexpr int KS   = MUL / 32;        // K-steps of 32
    constexpr int ROWS = WAVES_M * 16;    // fragment rows per WG tile

    const int tid  = threadIdx.x;
    const int lane = tid & 63;
    const int wid  = tid >> 6;
    const int wm   = wid % WAVES_M;
    const int wn   = wid / WAVES_M;
    const int l16  = lane & 15;
    const int quad = lane >> 4;
    const int lk8  = quad * 8;

    // ---- B fragments (weights * cnorm), loaded once, live in registers ----
    // B[k=u][n=v] = w[WO + v*MUL + u]; lane: n = lane&15, k = quad*8 + j.
    bf16x8 bfrag[NT][KS];
#pragma unroll
    for (int nt = 0; nt < NT; ++nt) {
        const int v = (wn * NT + nt) * 16 + l16;
        const float* wp = w + WO + (long)v * MUL;
#pragma unroll
        for (int ks = 0; ks < KS; ++ks) {
            const int u0 = ks * 32 + lk8;
#pragma unroll
            for (int j = 0; j < 8; ++j)
                bfrag[nt][ks][j] = (__bf16)(wp[u0 + j] * cnorm);
        }
    }

    // ---- persistent grid-stride loop over M-tiles ----
    for (int t = blockIdx.x; t < n_tiles; t += gridDim.x) {
        if (WAVES_N > 1) __syncthreads();   // keep waves lockstep for L1 reuse of shared A

        const int mbase = t * ROWS + wm * 16;

        // A fragments: A[m=lane&15][k=quad*8+j], m = mbase + l16, k = u.
        bf16x8 afrag[KS];
        {
            const int m = mbase + l16;
            if (D == 1) {
                const float* xp = x + (long)m * FEAT + XO;
#pragma unroll
                for (int ks = 0; ks < KS; ++ks) {
                    const float4 p0 = *(const float4*)(xp + ks * 32 + lk8);
                    const float4 p1 = *(const float4*)(xp + ks * 32 + lk8 + 4);
                    afrag[ks][0] = (__bf16)p0.x; afrag[ks][1] = (__bf16)p0.y;
                    afrag[ks][2] = (__bf16)p0.z; afrag[ks][3] = (__bf16)p0.w;
                    afrag[ks][4] = (__bf16)p1.x; afrag[ks][5] = (__bf16)p1.y;
                    afrag[ks][6] = (__bf16)p1.z; afrag[ks][7] = (__bf16)p1.w;
                }
            } else {
                const int b = m / D;
                const int i = m - b * D;
                const float* xp = x + (long)b * FEAT + XO + i;
#pragma unroll
                for (int ks = 0; ks < KS; ++ks) {
#pragma unroll
                    for (int j = 0; j < 8; ++j)
                        afrag[ks][j] = (__bf16)xp[(ks * 32 + lk8 + j) * D];
                }
            }
        }

        // ---- MFMA ----
        f32x4 acc[NT];
#pragma unroll
        for (int nt = 0; nt < NT; ++nt) acc[nt] = f32x4{0.f, 0.f, 0.f, 0.f};
#pragma unroll
        for (int ks = 0; ks < KS; ++ks)
#pragma unroll
            for (int nt = 0; nt < NT; ++nt)
                acc[nt] = __builtin_amdgcn_mfma_f32_16x16x32_bf16(
                    afrag[ks], bfrag[nt][ks], acc[nt], 0, 0, 0);

        // ---- store: D[row][col], col = lane&15, row = quad*4 + r ----
#pragma unroll
        for (int nt = 0; nt < NT; ++nt) {
            const int v = (wn * NT + nt) * 16 + l16;
#pragma unroll
            for (int r = 0; r < 4; ++r) {
                const int mm = mbase + quad * 4 + r;
                const int b = mm / D;
                const int i = mm - b * D;
                out[(long)b * FEAT + XO + v * D + i] = acc[nt][r];
            }
        }
    }
}

extern "C" void kernel_launch(void* const* d_in, const int* in_sizes, int n_in,
                              void* d_out, int out_size, void* d_ws, size_t ws_size,
                              hipStream_t stream) {
    const float* x = (const float*)d_in[0];
    const float* w = (const float*)d_in[1];
    float* out = (float*)d_out;

    // block 0: 256x0e  (M=131072, tiles of 16)  XO=0,   WO=0
    eqlin<256, 1, 0, 0, 1, 4, 4>
        <<<dim3(512), dim3(256), 0, stream>>>(x, w, out, 8192, 0.0625f);
    // block 1: 128x1o  (M=393216, tiles of 32)  XO=256, WO=65536
    eqlin<128, 3, 256, 65536, 2, 2, 4>
        <<<dim3(1024), dim3(256), 0, stream>>>(x, w, out, 12288, 0.088388347648318447f);
    // block 2: 64x2e   (M=655360, tiles of 64)  XO=640, WO=81920
    eqlin<64, 5, 640, 81920, 4, 1, 4>
        <<<dim3(2048), dim3(256), 0, stream>>>(x, w, out, 10240, 0.125f);
    // block 3: 32x3o   (M=917504, tiles of 64)  XO=960, WO=86016
    eqlin<32, 7, 960, 86016, 4, 1, 2>
        <<<dim3(2048), dim3(256), 0, stream>>>(x, w, out, 14336, 0.17677669529663689f);
}